// Round 6
// baseline (582.470 us; speedup 1.0000x reference)
//
#include <hip/hip_runtime.h>
#include <hip/hip_fp16.h>

typedef _Float16 half8 __attribute__((ext_vector_type(8)));
typedef __attribute__((ext_vector_type(4)))  float floatx4;
typedef __attribute__((ext_vector_type(16))) float floatx16;

#define BB 32
#define CC 256
#define OO 256
#define KS 7
#define HH 31
#define WW 31
#define HO 25
#define PP 625
#define SS 49

#define SLAB_PITCH 36        // ushort elems per pos row: 32 ci + 4 pad = 72 B
                             // (18-bank stride: ~2-way conflict, free; R5-verified 1.2e5)
#define SLAB_ROWS  372       // 128-p tile spans <= 12 x-rows; 12 x 31 = 372
#define P_TILE 128
#define NPX 5                // ceil(625/128)
#define KPD 20               // klds pitch in dwords (16 half2 + 4 pad)

// wt4 layout: [s][cb][kh][o][16ci]  (elems per (s,cb) = 2*256*16 = 8192)
#define WT4_ELEMS  ((size_t)SS * 8 * 2 * CC * 16)        // 3,211,264
#define WT4_BYTES  (WT4_ELEMS * 2)                       // 6,422,528
#define X16_ELEMS  ((size_t)BB * CC * HH * WW)           // 7,872,512
#define X16_BYTES  (X16_ELEMS * 2)                       // 15,745,024

static __device__ __forceinline__ unsigned pk2h(float lo, float hi) {
    __half2 h = __floats2half2_rn(lo, hi);    // v_cvt_pkrtz_f16_f32
    unsigned r;
    __builtin_memcpy(&r, &h, sizeof(r));
    return r;
}
static __device__ __forceinline__ unsigned mulh2(unsigned a, unsigned b) {
    __half2 x, y;
    __builtin_memcpy(&x, &a, 4); __builtin_memcpy(&y, &b, 4);
    __half2 r = __hmul2(x, y);                // v_pk_mul_f16
    unsigned u;
    __builtin_memcpy(&u, &r, 4);
    return u;
}
// modulated A-fragment: 8 fp16 = w[j] * k[j] via 4x v_pk_mul_f16
static __device__ __forceinline__ half8 mod8(uint4 w, uint4 k) {
    uint4 r;
    r.x = mulh2(w.x, k.x); r.y = mulh2(w.y, k.y);
    r.z = mulh2(w.z, k.z); r.w = mulh2(w.w, k.w);
    return __builtin_bit_cast(half8, r);
}

// ---------------------------------------------------------------------------
// Prepass A: w[o][c][s] f32 -> wt4[s][cb][kh][o][16] fp16. Grid 392.
// ---------------------------------------------------------------------------
__global__ __launch_bounds__(256) void repack_w(const float* __restrict__ w,
                                                unsigned short* __restrict__ wt4) {
    const int bid = blockIdx.x;           // = s*8 + cb
    const int s = bid >> 3, cb = bid & 7;
    const int o = threadIdx.x;
    const float* src = w + ((size_t)o * CC + cb * 32) * SS + s;
    float v[32];
#pragma unroll
    for (int ci = 0; ci < 32; ++ci) v[ci] = src[(size_t)ci * SS];
#pragma unroll
    for (int kh = 0; kh < 2; ++kh) {
        unsigned short* dst = wt4 + ((size_t)bid * 2 + kh) * (CC * 16) + o * 16;
        uint4 p0, p1;
        p0.x = pk2h(v[kh*16+0], v[kh*16+1]);  p0.y = pk2h(v[kh*16+2], v[kh*16+3]);
        p0.z = pk2h(v[kh*16+4], v[kh*16+5]);  p0.w = pk2h(v[kh*16+6], v[kh*16+7]);
        p1.x = pk2h(v[kh*16+8], v[kh*16+9]);  p1.y = pk2h(v[kh*16+10], v[kh*16+11]);
        p1.z = pk2h(v[kh*16+12], v[kh*16+13]); p1.w = pk2h(v[kh*16+14], v[kh*16+15]);
        *(uint4*)(dst)     = p0;
        *(uint4*)(dst + 8) = p1;
    }
}

// ---------------------------------------------------------------------------
// Prepass B: x f32 -> x16 fp16, same [b][c][pos] layout. 4 elems/thread,
// grid exact (total/4/256 = 7688), 16B-aligned float4 reads.
// ---------------------------------------------------------------------------
__global__ __launch_bounds__(256) void pack_x(const float* __restrict__ x,
                                              unsigned short* __restrict__ x16) {
    const size_t i4 = ((size_t)blockIdx.x * 256 + threadIdx.x) * 4;
    float4 v = *(const float4*)(x + i4);
    uint2 p;
    p.x = pk2h(v.x, v.y); p.y = pk2h(v.z, v.w);
    *(uint2*)(x16 + i4) = p;
}

// ---------------------------------------------------------------------------
// Fused main: block = 32o x 128p of one batch, 4 waves = 4 p-subtiles
// (wave = 32o x 32p, all 49 s, acc 1x16). No kw split -> no reduction.
// Per s-step per wave: 2 global uint4 A (wt4 o-slice, 2-deep reg prefetch),
// 2 ds b128 k-broadcast, 2 ds b128 B, 8 v_pk_mul_f16, 2 mfma_32x32x16_f16.
// oy = id%8 -> per-XCD wt4 slice = 0.8 MB, L2-resident (R4/R5's measured
// killer was wt4 HBM re-fetch: FETCH 120-150 MB vs 6.4 MB wt4).
// Grid 1280 = 32b x 8oy x 5px = EXACTLY 5 blocks/CU co-resident
// (lds 30.7K x 5 = 153.5K <= 160K; lb(256,5) VGPR cap 102) = 62% occ.
// ---------------------------------------------------------------------------
__global__ __launch_bounds__(256, 5) void dwconv_fused(
        const unsigned short* __restrict__ x16,
        const unsigned short* __restrict__ wt4,
        const float* __restrict__ kern, const float* __restrict__ bias,
        float* __restrict__ out) {
    __shared__ unsigned short slab[SLAB_ROWS * SLAB_PITCH];   // 26784 B
    __shared__ unsigned klds[SS * KPD];                       // 3920 B

    const int tid = threadIdx.x;
    const int id = blockIdx.x;
    const int oy = id & 7;                    // XCD slice: 32 o, 0.8 MB wt4
    const int m = id >> 3;                    // 0..159; consecutive m on one
    const int b = m / NPX, px = m - (m / NPX) * NPX;  // XCD share x[b] in L2

    const int p0 = px * P_TILE;
    const int h0 = p0 / HO;
    const int pmax = (p0 + P_TILE - 1 < PP - 1) ? p0 + P_TILE - 1 : PP - 1;
    const int rows = pmax / HO - h0 + 7;          // <= 12
    const int npos = rows * WW;

    const int lane = tid & 63, wid = tid >> 6;    // wid = p-subtile 0..3
    const int l32 = lane & 31, half = lane >> 5;

    // B-fragment LDS offset (ushort elems) for this wave's 32-p subtile
    int bOff;
    {
        int p = p0 + wid * 32 + l32;
        if (p > PP - 1) p = PP - 1;               // clamp; store guarded later
        int h = p / HO, ww_ = p - h * HO;
        bOff = ((h - h0) * WW + ww_) * SLAB_PITCH + half * 8;
    }

    // A base: rows (oy*32 + l32); kh -> +4096; per-s stride 65536; cb*8192
    const unsigned short* wbase = wt4 + (size_t)(oy * 32 + l32) * 16 + half * 8;

    floatx16 acc;
#pragma unroll
    for (int rr = 0; rr < 16; ++rr) acc[rr] = 0.f;

    for (int cb = 0; cb < 8; ++cb) {
        __syncthreads();   // prior compute done: slab/klds safe to overwrite
        // ---- stage x slab: slab[pos][ci] fp16, 4 waves x 8 channels ----
        {
            const unsigned short* xsrc = x16
                + ((size_t)(b * CC + cb * 32 + wid * 8)) * (HH * WW) + h0 * WW;
#pragma unroll
            for (int it = 0; it < 6; ++it) {
                int pos = lane + it * 64;
                if (pos < npos) {
                    unsigned short v[8];
#pragma unroll
                    for (int j = 0; j < 8; ++j) v[j] = xsrc[j * (HH * WW) + pos];
                    uint4 pkt;
                    pkt.x = (unsigned)v[0] | ((unsigned)v[1] << 16);
                    pkt.y = (unsigned)v[2] | ((unsigned)v[3] << 16);
                    pkt.z = (unsigned)v[4] | ((unsigned)v[5] << 16);
                    pkt.w = (unsigned)v[6] | ((unsigned)v[7] << 16);
                    *(uint4*)(slab + pos * SLAB_PITCH + wid * 8) = pkt;
                }
            }
        }
        // ---- stage k table: klds[s][16 half2] for this (b, cb) ----
        {
            const float* ksrc = kern + ((size_t)(b * CC + cb * 32)) * SS;
#pragma unroll
            for (int it = 0; it < 4; ++it) {
                int f = tid + it * 256;
                if (f < 16 * SS) {
                    int s = f >> 4, pr = f & 15;
                    float v0 = ksrc[(size_t)(pr * 2) * SS + s];
                    float v1 = ksrc[(size_t)(pr * 2 + 1) * SS + s];
                    klds[s * KPD + pr] = pk2h(v0, v1);
                }
            }
        }
        __syncthreads();

        const unsigned short* aptr = wbase + (size_t)cb * 8192;   // s = 0
        uint4 a0k0 = *(const uint4*)(aptr);                 // s,   kh0
        uint4 a0k1 = *(const uint4*)(aptr + 4096);          // s,   kh1
        uint4 a1k0 = *(const uint4*)(aptr + 65536);         // s+1, kh0
        uint4 a1k1 = *(const uint4*)(aptr + 65536 + 4096);  // s+1, kh1

        int kk = 0, ll = 0;
        for (int si = 0; si < SS; ++si) {
            // prefetch s+2 A-frags (L2-resident 0.8 MB slice)
            uint4 n0, n1;
            if (si + 2 < SS) {
                const unsigned short* p2 = aptr + 2 * 65536;
                n0 = *(const uint4*)(p2);
                n1 = *(const uint4*)(p2 + 4096);
            } else {
                n0 = a1k0; n1 = a1k1;
            }

            // k for this s: 16B broadcast per kh (channels kh*16+half*8..+7)
            const unsigned* kp = klds + (size_t)si * KPD;
            uint4 kv0 = *(const uint4*)(kp + half * 4);
            uint4 kv1 = *(const uint4*)(kp + 8 + half * 4);

            const unsigned short* slabS = slab + (kk * WW + ll) * SLAB_PITCH;
            half8 b0 = *(const half8*)(slabS + bOff);          // kh0
            half8 b1 = *(const half8*)(slabS + bOff + 16);     // kh1

            half8 a0 = mod8(a0k0, kv0);
            half8 a1 = mod8(a0k1, kv1);

            acc = __builtin_amdgcn_mfma_f32_32x32x16_f16(a0, b0, acc, 0, 0, 0);
            acc = __builtin_amdgcn_mfma_f32_32x32x16_f16(a1, b1, acc, 0, 0, 0);

            a0k0 = a1k0; a0k1 = a1k1; a1k0 = n0; a1k1 = n1;
            aptr += 65536;
            if (++ll == KS) { ll = 0; ++kk; }
        }
    }

    // ---- epilogue: direct store ----
    // C/D 32x32 mapping: col = l32 (p), row = (reg&3) + 8*(reg>>2) + 4*half (o)
    const int pout = p0 + wid * 32 + l32;
    if (pout < PP) {
#pragma unroll
        for (int c = 0; c < 4; ++c) {
            const int ob = oy * 32 + c * 8 + 4 * half;
            const float4 bv = *(const float4*)(bias + ob);
            out[((size_t)(b * OO + ob + 0)) * PP + pout] = acc[4*c+0] + bv.x;
            out[((size_t)(b * OO + ob + 1)) * PP + pout] = acc[4*c+1] + bv.y;
            out[((size_t)(b * OO + ob + 2)) * PP + pout] = acc[4*c+2] + bv.z;
            out[((size_t)(b * OO + ob + 3)) * PP + pout] = acc[4*c+3] + bv.w;
        }
    }
}

// ---------------------------------------------------------------------------
// Last-resort fallback: naive but correct (ws too small for wt4+x16).
// ---------------------------------------------------------------------------
__global__ __launch_bounds__(256) void dwconv_naive(
        const float* __restrict__ x, const float* __restrict__ kern,
        const float* __restrict__ w, const float* __restrict__ bias,
        float* __restrict__ out) {
    const int idx = blockIdx.x * 256 + threadIdx.x;
    if (idx >= BB * OO * PP) return;
    const int p = idx % PP;
    const int o = (idx / PP) % OO;
    const int b = idx / (PP * OO);
    const int h = p / HO;
    const int wq = p - h * HO;
    float acc = 0.f;
    for (int c = 0; c < CC; ++c) {
        const float* xp = x + ((size_t)(b * CC + c)) * (HH * WW) + h * WW + wq;
        const float* kp = kern + ((size_t)b * CC + c) * SS;
        const float* wp = w + ((size_t)o * CC + c) * SS;
#pragma unroll
        for (int s = 0; s < SS; ++s) {
            const int kk = s / KS;
            const int ll = s - kk * KS;
            acc += xp[kk * WW + ll] * kp[s] * wp[s];
        }
    }
    out[idx] = acc + bias[o];
}

extern "C" void kernel_launch(void* const* d_in, const int* in_sizes, int n_in,
                              void* d_out, int out_size, void* d_ws, size_t ws_size,
                              hipStream_t stream) {
    const float* x    = (const float*)d_in[0];
    const float* kern = (const float*)d_in[1];
    const float* w    = (const float*)d_in[2];
    const float* bias = (const float*)d_in[3];
    float* out = (float*)d_out;

    if (ws_size >= WT4_BYTES + X16_BYTES) {
        unsigned short* wt4 = (unsigned short*)d_ws;
        unsigned short* x16 = (unsigned short*)((char*)d_ws + WT4_BYTES);
        repack_w<<<dim3(SS * 8), dim3(256), 0, stream>>>(w, wt4);
        pack_x<<<dim3((unsigned)(X16_ELEMS / 4 / 256)), dim3(256), 0, stream>>>(x, x16);
        dwconv_fused<<<dim3(1280), dim3(256), 0, stream>>>(x16, wt4, kern, bias, out);
    } else {
        const int total = BB * OO * PP;
        dwconv_naive<<<dim3((total + 255) / 256), dim3(256), 0, stream>>>(
            x, kern, w, bias, out);
    }
}

// Round 7
// 384.807 us; speedup vs baseline: 1.5137x; 1.5137x over previous
//
#include <hip/hip_runtime.h>
#include <hip/hip_fp16.h>

typedef _Float16 half8 __attribute__((ext_vector_type(8)));
typedef __attribute__((ext_vector_type(4)))  float floatx4;
typedef __attribute__((ext_vector_type(16))) float floatx16;

#define BB 32
#define CC 256
#define OO 256
#define KS 7
#define HH 31
#define WW 31
#define HO 25
#define PP 625
#define SS 49

#define SLAB_PITCH 36        // ushort elems per pos row: 32 ci + 4 pad = 72 B
                             // (18-bank stride; R5-verified ~1e5 conflicts)
#define SLAB_ROWS  310       // 64-p tile spans <= 10 x-rows; 10 x 31 = 310
#define KPD 20               // klds pitch in dwords (16 half2 + 4 pad)

// wt4 layout: [s][cb][kh][o][16ci]  (elems per (s,cb) = 2*256*16 = 8192)
#define WT4_ELEMS  ((size_t)SS * 8 * 2 * CC * 16)        // 3,211,264
#define WT4_BYTES  (WT4_ELEMS * 2)                       // 6,422,528

static __device__ __forceinline__ unsigned pk2h(float lo, float hi) {
    __half2 h = __floats2half2_rn(lo, hi);    // v_cvt_pkrtz_f16_f32
    unsigned r;
    __builtin_memcpy(&r, &h, sizeof(r));
    return r;
}
static __device__ __forceinline__ unsigned mulh2(unsigned a, unsigned b) {
    __half2 x, y;
    __builtin_memcpy(&x, &a, 4); __builtin_memcpy(&y, &b, 4);
    __half2 r = __hmul2(x, y);                // v_pk_mul_f16
    unsigned u;
    __builtin_memcpy(&u, &r, 4);
    return u;
}
// modulated A-fragment: 8 fp16 = w[j] * k[j] via 4x v_pk_mul_f16
static __device__ __forceinline__ half8 mod8(uint4 w, uint4 k) {
    uint4 r;
    r.x = mulh2(w.x, k.x); r.y = mulh2(w.y, k.y);
    r.z = mulh2(w.z, k.z); r.w = mulh2(w.w, k.w);
    return __builtin_bit_cast(half8, r);
}

// ---------------------------------------------------------------------------
// Prepass: w[o][c][s] f32 -> wt4[s][cb][kh][o][16] fp16. Grid 392.
// ---------------------------------------------------------------------------
__global__ __launch_bounds__(256) void repack_w(const float* __restrict__ w,
                                                unsigned short* __restrict__ wt4) {
    const int bid = blockIdx.x;           // = s*8 + cb
    const int s = bid >> 3, cb = bid & 7;
    const int o = threadIdx.x;
    const float* src = w + ((size_t)o * CC + cb * 32) * SS + s;
    float v[32];
#pragma unroll
    for (int ci = 0; ci < 32; ++ci) v[ci] = src[(size_t)ci * SS];
#pragma unroll
    for (int kh = 0; kh < 2; ++kh) {
        unsigned short* dst = wt4 + ((size_t)bid * 2 + kh) * (CC * 16) + o * 16;
        uint4 p0, p1;
        p0.x = pk2h(v[kh*16+0], v[kh*16+1]);  p0.y = pk2h(v[kh*16+2], v[kh*16+3]);
        p0.z = pk2h(v[kh*16+4], v[kh*16+5]);  p0.w = pk2h(v[kh*16+6], v[kh*16+7]);
        p1.x = pk2h(v[kh*16+8], v[kh*16+9]);  p1.y = pk2h(v[kh*16+10], v[kh*16+11]);
        p1.z = pk2h(v[kh*16+12], v[kh*16+13]); p1.w = pk2h(v[kh*16+14], v[kh*16+15]);
        *(uint4*)(dst)     = p0;
        *(uint4*)(dst + 8) = p1;
    }
}

// ---------------------------------------------------------------------------
// Fused main (R2-big structure + in-loop modulation): block = 64o x 64p of
// one batch, 4 waves k-split over s (quarters 13/12/12/12). Per s-step per
// wave: 4 global b128 A (wt4, 1.6 MB per-XCD slice, L2-hot, 1-step reg
// prefetch), 2 ds b128 k-broadcast, 16 v_pk_mul_f16 modulation, 4 ds b128 B,
// 8x mfma_32x32x16_f16 into 4 indep acc chains. The 8-MFMA body (~256 cyc)
// is what hides ds/VALU latency — R3-R6 showed small bodies (2-4 MFMA)
// stall regardless of occupancy (R6: 48% occ, 10% MfmaUtil).
// Grid 1280; id = hi*80 + px*8 + g7 -> XCD = g7: one oy per XCD (1.6 MB
// wt4 slice L2-pinned), 10 px blocks of a (b,oy) group co-XCD.
// Epilogue: 4-way kw reduction via LDS (R2-verified).
// ---------------------------------------------------------------------------
__global__ __launch_bounds__(256, 3) void dwconv_fused(
        const float* __restrict__ x, const unsigned short* __restrict__ wt4,
        const float* __restrict__ kern, const float* __restrict__ bias,
        float* __restrict__ out) {
    __shared__ unsigned short slab[SLAB_ROWS * SLAB_PITCH];   // 22320 B
    __shared__ unsigned klds[SS * KPD];                       // 3920 B

    const int tid = threadIdx.x;
    const int id = blockIdx.x;
    // id = hi*80 + px*8 + g7; g = hi*8 + g7 = b*4 + oy -> same-XCD groups
    const int hi = id / 80, rem = id % 80;
    const int px = rem >> 3;
    const int g = hi * 8 + (rem & 7);
    const int b = g >> 2, oy = g & 3;

    const int p0 = px * 64, o0 = oy * 64;
    const int h0 = p0 / HO;
    const int pmax = (p0 + 63 < PP - 1) ? p0 + 63 : PP - 1;
    const int rows = pmax / HO - h0 + 7;          // <= 10
    const int npos = rows * WW;

    const int lane = tid & 63, kw = tid >> 6;
    const int l32 = lane & 31, half = lane >> 5;

    // B-fragment LDS offsets (ushort elems) for 2 p-subtiles of 32
    int bOff[2];
#pragma unroll
    for (int ph = 0; ph < 2; ++ph) {
        int p = p0 + ph * 32 + l32;
        if (p > PP - 1) p = PP - 1;               // clamp; store guarded later
        int h = p / HO, ww_ = p - h * HO;
        bOff[ph] = ((h - h0) * WW + ww_) * SLAB_PITCH + half * 8;
    }

    const int s0 = kw * 12 + (kw > 0 ? 1 : 0);    // 0,13,25,37
    const int ns = kw ? 12 : 13;

    // A base: rows (o0 + oh*32 + l32); oh -> +512, kh -> +4096;
    // per-s stride 65536; per-cb offset cb*8192   (wt4[s][cb][kh][o][16])
    const unsigned short* wbase = wt4 + (size_t)(o0 + l32) * 16 + half * 8;

    floatx16 acc[2][2];
#pragma unroll
    for (int oh = 0; oh < 2; ++oh)
#pragma unroll
        for (int ph = 0; ph < 2; ++ph)
#pragma unroll
            for (int r = 0; r < 16; ++r) acc[oh][ph][r] = 0.f;

    for (int cb = 0; cb < 8; ++cb) {
        __syncthreads();   // prior compute done: slab/klds safe to overwrite
        // ---- stage x slab: slab[pos][ci] fp16, 4 waves x 8 channels ----
        {
            const float* xsrc = x + ((size_t)(b * CC + cb * 32 + kw * 8)) * (HH * WW)
                                  + h0 * WW;
#pragma unroll
            for (int it = 0; it < 5; ++it) {
                int pos = lane + it * 64;
                if (pos < npos) {
                    float v[8];
#pragma unroll
                    for (int j = 0; j < 8; ++j) v[j] = xsrc[j * (HH * WW) + pos];
                    uint4 pkt;
                    pkt.x = pk2h(v[0], v[1]); pkt.y = pk2h(v[2], v[3]);
                    pkt.z = pk2h(v[4], v[5]); pkt.w = pk2h(v[6], v[7]);
                    *(uint4*)(slab + pos * SLAB_PITCH + kw * 8) = pkt;
                }
            }
        }
        // ---- stage k table: klds[s][16 half2] for this (b, cb) ----
        {
            const float* ksrc = kern + ((size_t)(b * CC + cb * 32)) * SS;
#pragma unroll
            for (int it = 0; it < 4; ++it) {
                int f = tid + it * 256;
                if (f < 16 * SS) {
                    int s = f >> 4, pr = f & 15;
                    float v0 = ksrc[(size_t)(pr * 2) * SS + s];
                    float v1 = ksrc[(size_t)(pr * 2 + 1) * SS + s];
                    klds[s * KPD + pr] = pk2h(v0, v1);
                }
            }
        }
        __syncthreads();

        // rolling A pointer for this wave's s-quarter
        const unsigned short* aptr = wbase + (size_t)(s0 * 8 + cb) * 8192;

        uint4 wa0 = *(const uint4*)(aptr);          // oh0 kh0
        uint4 wa1 = *(const uint4*)(aptr + 512);    // oh1 kh0
        uint4 wa2 = *(const uint4*)(aptr + 4096);   // oh0 kh1
        uint4 wa3 = *(const uint4*)(aptr + 4608);   // oh1 kh1

        int s = s0, kk = s0 / KS, ll = s0 - (s0 / KS) * KS;
        for (int si = 0; si < ns; ++si) {
            // prefetch s+1 A-frags (L2-resident wt4 slice)
            uint4 wn0, wn1, wn2, wn3;
            if (si + 1 < ns) {
                aptr += 65536;
                wn0 = *(const uint4*)(aptr);
                wn1 = *(const uint4*)(aptr + 512);
                wn2 = *(const uint4*)(aptr + 4096);
                wn3 = *(const uint4*)(aptr + 4608);
            } else {
                wn0 = wa0; wn1 = wa1; wn2 = wa2; wn3 = wa3;
            }

            // k broadcast for this s (pairs kh*8 + half*4 + 0..3)
            const unsigned* kp = klds + (size_t)s * KPD;
            uint4 kv0 = *(const uint4*)(kp + half * 4);        // kh0
            uint4 kv1 = *(const uint4*)(kp + 8 + half * 4);    // kh1

            const unsigned short* slabS = slab + (kk * WW + ll) * SLAB_PITCH;
            half8 sb00 = *(const half8*)(slabS + bOff[0]);        // ph0 kh0
            half8 sb01 = *(const half8*)(slabS + bOff[0] + 16);   // ph0 kh1
            half8 sb10 = *(const half8*)(slabS + bOff[1]);        // ph1 kh0
            half8 sb11 = *(const half8*)(slabS + bOff[1] + 16);   // ph1 kh1

            half8 a00 = mod8(wa0, kv0);  // oh0 kh0
            half8 a10 = mod8(wa1, kv0);  // oh1 kh0
            half8 a01 = mod8(wa2, kv1);  // oh0 kh1
            half8 a11 = mod8(wa3, kv1);  // oh1 kh1

            acc[0][0] = __builtin_amdgcn_mfma_f32_32x32x16_f16(a00, sb00, acc[0][0], 0, 0, 0);
            acc[0][1] = __builtin_amdgcn_mfma_f32_32x32x16_f16(a00, sb10, acc[0][1], 0, 0, 0);
            acc[1][0] = __builtin_amdgcn_mfma_f32_32x32x16_f16(a10, sb00, acc[1][0], 0, 0, 0);
            acc[1][1] = __builtin_amdgcn_mfma_f32_32x32x16_f16(a10, sb10, acc[1][1], 0, 0, 0);
            acc[0][0] = __builtin_amdgcn_mfma_f32_32x32x16_f16(a01, sb01, acc[0][0], 0, 0, 0);
            acc[0][1] = __builtin_amdgcn_mfma_f32_32x32x16_f16(a01, sb11, acc[0][1], 0, 0, 0);
            acc[1][0] = __builtin_amdgcn_mfma_f32_32x32x16_f16(a11, sb01, acc[1][0], 0, 0, 0);
            acc[1][1] = __builtin_amdgcn_mfma_f32_32x32x16_f16(a11, sb11, acc[1][1], 0, 0, 0);

            wa0 = wn0; wa1 = wn1; wa2 = wn2; wa3 = wn3;
            ++s; if (++ll == KS) { ll = 0; ++kk; }
        }
    }

    // ---- epilogue: 4-way kw reduction via LDS (reuse slab as red[64p][68]) --
    float* red = (float*)slab;
    __syncthreads();
    if (kw == 3) {
#pragma unroll
        for (int oh = 0; oh < 2; ++oh)
#pragma unroll
            for (int ph = 0; ph < 2; ++ph)
#pragma unroll
                for (int c = 0; c < 4; ++c) {
                    floatx4 v4 = {acc[oh][ph][4*c+0], acc[oh][ph][4*c+1],
                                  acc[oh][ph][4*c+2], acc[oh][ph][4*c+3]};
                    *(floatx4*)(red + (ph * 32 + l32) * 68 + oh * 32 + c * 8 + 4 * half) = v4;
                }
    }
    __syncthreads();
    if (kw == 2) {
#pragma unroll
        for (int oh = 0; oh < 2; ++oh)
#pragma unroll
            for (int ph = 0; ph < 2; ++ph)
#pragma unroll
                for (int c = 0; c < 4; ++c) {
                    float* rp = red + (ph * 32 + l32) * 68 + oh * 32 + c * 8 + 4 * half;
                    floatx4 v4 = *(floatx4*)rp;
                    v4[0] += acc[oh][ph][4*c+0]; v4[1] += acc[oh][ph][4*c+1];
                    v4[2] += acc[oh][ph][4*c+2]; v4[3] += acc[oh][ph][4*c+3];
                    *(floatx4*)rp = v4;
                }
    }
    __syncthreads();
    if (kw == 1) {
#pragma unroll
        for (int oh = 0; oh < 2; ++oh)
#pragma unroll
            for (int ph = 0; ph < 2; ++ph)
#pragma unroll
                for (int c = 0; c < 4; ++c) {
                    float* rp = red + (ph * 32 + l32) * 68 + oh * 32 + c * 8 + 4 * half;
                    floatx4 v4 = *(floatx4*)rp;
                    v4[0] += acc[oh][ph][4*c+0]; v4[1] += acc[oh][ph][4*c+1];
                    v4[2] += acc[oh][ph][4*c+2]; v4[3] += acc[oh][ph][4*c+3];
                    *(floatx4*)rp = v4;
                }
    }
    __syncthreads();
    if (kw == 0) {
#pragma unroll
        for (int oh = 0; oh < 2; ++oh)
#pragma unroll
            for (int c = 0; c < 4; ++c) {
                const int ob = o0 + oh * 32 + c * 8 + 4 * half;
                const float4 bv = *(const float4*)(bias + ob);
#pragma unroll
                for (int ph = 0; ph < 2; ++ph) {
                    const int p = p0 + ph * 32 + l32;
                    floatx4 v4 = *(floatx4*)(red + (ph * 32 + l32) * 68 + oh * 32 + c * 8 + 4 * half);
                    if (p < PP) {
                        out[((size_t)(b * OO + ob + 0)) * PP + p] = v4[0] + acc[oh][ph][4*c+0] + bv.x;
                        out[((size_t)(b * OO + ob + 1)) * PP + p] = v4[1] + acc[oh][ph][4*c+1] + bv.y;
                        out[((size_t)(b * OO + ob + 2)) * PP + p] = v4[2] + acc[oh][ph][4*c+2] + bv.z;
                        out[((size_t)(b * OO + ob + 3)) * PP + p] = v4[3] + acc[oh][ph][4*c+3] + bv.w;
                    }
                }
            }
    }
}

// ---------------------------------------------------------------------------
// Last-resort fallback: naive but correct (ws too small for wt4).
// ---------------------------------------------------------------------------
__global__ __launch_bounds__(256) void dwconv_naive(
        const float* __restrict__ x, const float* __restrict__ kern,
        const float* __restrict__ w, const float* __restrict__ bias,
        float* __restrict__ out) {
    const int idx = blockIdx.x * 256 + threadIdx.x;
    if (idx >= BB * OO * PP) return;
    const int p = idx % PP;
    const int o = (idx / PP) % OO;
    const int b = idx / (PP * OO);
    const int h = p / HO;
    const int wq = p - h * HO;
    float acc = 0.f;
    for (int c = 0; c < CC; ++c) {
        const float* xp = x + ((size_t)(b * CC + c)) * (HH * WW) + h * WW + wq;
        const float* kp = kern + ((size_t)b * CC + c) * SS;
        const float* wp = w + ((size_t)o * CC + c) * SS;
#pragma unroll
        for (int s = 0; s < SS; ++s) {
            const int kk = s / KS;
            const int ll = s - kk * KS;
            acc += xp[kk * WW + ll] * kp[s] * wp[s];
        }
    }
    out[idx] = acc + bias[o];
}

extern "C" void kernel_launch(void* const* d_in, const int* in_sizes, int n_in,
                              void* d_out, int out_size, void* d_ws, size_t ws_size,
                              hipStream_t stream) {
    const float* x    = (const float*)d_in[0];
    const float* kern = (const float*)d_in[1];
    const float* w    = (const float*)d_in[2];
    const float* bias = (const float*)d_in[3];
    float* out = (float*)d_out;

    if (ws_size >= WT4_BYTES) {
        unsigned short* wt4 = (unsigned short*)d_ws;
        repack_w<<<dim3(SS * 8), dim3(256), 0, stream>>>(w, wt4);
        dwconv_fused<<<dim3(1280), dim3(256), 0, stream>>>(x, wt4, kern, bias, out);
    } else {
        const int total = BB * OO * PP;
        dwconv_naive<<<dim3((total + 255) / 256), dim3(256), 0, stream>>>(
            x, kern, w, bias, out);
    }
}

// Round 8
// 344.935 us; speedup vs baseline: 1.6886x; 1.1156x over previous
//
#include <hip/hip_runtime.h>
#include <hip/hip_fp16.h>

typedef _Float16 half8 __attribute__((ext_vector_type(8)));
typedef __attribute__((ext_vector_type(4)))  float floatx4;
typedef __attribute__((ext_vector_type(16))) float floatx16;

#define BB 32
#define CC 256
#define OO 256
#define KS 7
#define HH 31
#define WW 31
#define HO 25
#define PP 625
#define SS 49

#define SLAB_PITCH 36        // ushort elems per pos row: 32 ci + 4 pad = 72 B
#define SLAB_ROWS  310       // 64-p tile spans <= 10 x-rows; 10 x 31 = 310
#define KPD 20               // klds pitch in dwords (16 half2 + 4 pad)

// wt4 layout: [s][cb][kh][o][16ci]  (elems per (s,cb) = 2*256*16 = 8192)
#define WT4_ELEMS  ((size_t)SS * 8 * 2 * CC * 16)        // 3,211,264
#define WT4_BYTES  (WT4_ELEMS * 2)                       // 6,422,528

static __device__ __forceinline__ unsigned pk2h(float lo, float hi) {
    __half2 h = __floats2half2_rn(lo, hi);    // v_cvt_pkrtz_f16_f32
    unsigned r;
    __builtin_memcpy(&r, &h, sizeof(r));
    return r;
}
static __device__ __forceinline__ unsigned mulh2(unsigned a, unsigned b) {
    __half2 x, y;
    __builtin_memcpy(&x, &a, 4); __builtin_memcpy(&y, &b, 4);
    __half2 r = __hmul2(x, y);                // v_pk_mul_f16
    unsigned u;
    __builtin_memcpy(&u, &r, 4);
    return u;
}
// modulated A-fragment: 8 fp16 = w[j] * k[j] via 4x v_pk_mul_f16
static __device__ __forceinline__ half8 mod8(uint4 w, uint4 k) {
    uint4 r;
    r.x = mulh2(w.x, k.x); r.y = mulh2(w.y, k.y);
    r.z = mulh2(w.z, k.z); r.w = mulh2(w.w, k.w);
    return __builtin_bit_cast(half8, r);
}

// ---------------------------------------------------------------------------
// Prepass: w[o][c][s] f32 -> wt4[s][cb][kh][o][16] fp16. Grid 392.
// ---------------------------------------------------------------------------
__global__ __launch_bounds__(256) void repack_w(const float* __restrict__ w,
                                                unsigned short* __restrict__ wt4) {
    const int bid = blockIdx.x;           // = s*8 + cb
    const int s = bid >> 3, cb = bid & 7;
    const int o = threadIdx.x;
    const float* src = w + ((size_t)o * CC + cb * 32) * SS + s;
    float v[32];
#pragma unroll
    for (int ci = 0; ci < 32; ++ci) v[ci] = src[(size_t)ci * SS];
#pragma unroll
    for (int kh = 0; kh < 2; ++kh) {
        unsigned short* dst = wt4 + ((size_t)bid * 2 + kh) * (CC * 16) + o * 16;
        uint4 p0, p1;
        p0.x = pk2h(v[kh*16+0], v[kh*16+1]);  p0.y = pk2h(v[kh*16+2], v[kh*16+3]);
        p0.z = pk2h(v[kh*16+4], v[kh*16+5]);  p0.w = pk2h(v[kh*16+6], v[kh*16+7]);
        p1.x = pk2h(v[kh*16+8], v[kh*16+9]);  p1.y = pk2h(v[kh*16+10], v[kh*16+11]);
        p1.z = pk2h(v[kh*16+12], v[kh*16+13]); p1.w = pk2h(v[kh*16+14], v[kh*16+15]);
        *(uint4*)(dst)     = p0;
        *(uint4*)(dst + 8) = p1;
    }
}

// ---------------------------------------------------------------------------
// Fused main (R7 + FULL s+1 register pipeline): block = 64o x 64p, 4 waves
// k-split. Per step: compute uses ONLY registers loaded in the previous
// step (A-global, k-ds, B-ds all prefetched) -> the in-step lgkm wait that
// serialized R3-R7 (R7: 17% MfmaUtil, all pipes idle) is hidden under the
// 8-MFMA + 16-pk_mul body. lb(256,2): ~185 unified regs, 2 blocks/CU;
// per-CU model: 8 waves x (8 MFMA = 64.6 cyc + 6 ds b128 = 72 cyc LDS pipe)
// -> MFMA/LDS co-limited ~55-75 us loop time.
// ---------------------------------------------------------------------------
__global__ __launch_bounds__(256, 2) void dwconv_fused(
        const float* __restrict__ x, const unsigned short* __restrict__ wt4,
        const float* __restrict__ kern, const float* __restrict__ bias,
        float* __restrict__ out) {
    __shared__ unsigned short slab[SLAB_ROWS * SLAB_PITCH];   // 22320 B
    __shared__ unsigned klds[SS * KPD];                       // 3920 B

    const int tid = threadIdx.x;
    const int id = blockIdx.x;
    // id = hi*80 + px*8 + g7; g = hi*8 + g7 = b*4 + oy -> same-XCD groups
    const int hi = id / 80, rem = id % 80;
    const int px = rem >> 3;
    const int g = hi * 8 + (rem & 7);
    const int b = g >> 2, oy = g & 3;

    const int p0 = px * 64, o0 = oy * 64;
    const int h0 = p0 / HO;
    const int pmax = (p0 + 63 < PP - 1) ? p0 + 63 : PP - 1;
    const int rows = pmax / HO - h0 + 7;          // <= 10
    const int npos = rows * WW;

    const int lane = tid & 63, kw = tid >> 6;
    const int l32 = lane & 31, half = lane >> 5;

    // B-fragment LDS offsets (ushort elems) for 2 p-subtiles of 32
    int bOff[2];
#pragma unroll
    for (int ph = 0; ph < 2; ++ph) {
        int p = p0 + ph * 32 + l32;
        if (p > PP - 1) p = PP - 1;               // clamp; store guarded later
        int h = p / HO, ww_ = p - h * HO;
        bOff[ph] = ((h - h0) * WW + ww_) * SLAB_PITCH + half * 8;
    }

    const int s0 = kw * 12 + (kw > 0 ? 1 : 0);    // 0,13,25,37
    const int ns = kw ? 12 : 13;

    // A base: rows (o0 + oh*32 + l32); oh -> +512, kh -> +4096;
    // per-s stride 65536; per-cb offset cb*8192   (wt4[s][cb][kh][o][16])
    const unsigned short* wbase = wt4 + (size_t)(o0 + l32) * 16 + half * 8;

    floatx16 acc[2][2];
#pragma unroll
    for (int oh = 0; oh < 2; ++oh)
#pragma unroll
        for (int ph = 0; ph < 2; ++ph)
#pragma unroll
            for (int r = 0; r < 16; ++r) acc[oh][ph][r] = 0.f;

    for (int cb = 0; cb < 8; ++cb) {
        __syncthreads();   // prior compute done: slab/klds safe to overwrite
        // ---- stage x slab: slab[pos][ci] fp16, 4 waves x 8 channels ----
        {
            const float* xsrc = x + ((size_t)(b * CC + cb * 32 + kw * 8)) * (HH * WW)
                                  + h0 * WW;
#pragma unroll
            for (int it = 0; it < 5; ++it) {
                int pos = lane + it * 64;
                if (pos < npos) {
                    float v[8];
#pragma unroll
                    for (int j = 0; j < 8; ++j) v[j] = xsrc[j * (HH * WW) + pos];
                    uint4 pkt;
                    pkt.x = pk2h(v[0], v[1]); pkt.y = pk2h(v[2], v[3]);
                    pkt.z = pk2h(v[4], v[5]); pkt.w = pk2h(v[6], v[7]);
                    *(uint4*)(slab + pos * SLAB_PITCH + kw * 8) = pkt;
                }
            }
        }
        // ---- stage k table: klds[s][16 half2] for this (b, cb) ----
        {
            const float* ksrc = kern + ((size_t)(b * CC + cb * 32)) * SS;
#pragma unroll
            for (int it = 0; it < 4; ++it) {
                int f = tid + it * 256;
                if (f < 16 * SS) {
                    int s = f >> 4, pr = f & 15;
                    float v0 = ksrc[(size_t)(pr * 2) * SS + s];
                    float v1 = ksrc[(size_t)(pr * 2 + 1) * SS + s];
                    klds[s * KPD + pr] = pk2h(v0, v1);
                }
            }
        }
        __syncthreads();

        // ---- per-cb pipeline prologue: load step s0 operands into regs ----
        const unsigned short* aptr = wbase + (size_t)(s0 * 8 + cb) * 8192;
        int kk = s0 / KS, ll = s0 - (s0 / KS) * KS;

        uint4 wa0 = *(const uint4*)(aptr);          // oh0 kh0
        uint4 wa1 = *(const uint4*)(aptr + 512);    // oh1 kh0
        uint4 wa2 = *(const uint4*)(aptr + 4096);   // oh0 kh1
        uint4 wa3 = *(const uint4*)(aptr + 4608);   // oh1 kh1

        const unsigned* kp = klds + (size_t)s0 * KPD;
        uint4 kc0 = *(const uint4*)(kp + half * 4);        // kh0
        uint4 kc1 = *(const uint4*)(kp + 8 + half * 4);    // kh1

        const unsigned short* slabS = slab + (kk * WW + ll) * SLAB_PITCH;
        half8 bc00 = *(const half8*)(slabS + bOff[0]);        // ph0 kh0
        half8 bc01 = *(const half8*)(slabS + bOff[0] + 16);   // ph0 kh1
        half8 bc10 = *(const half8*)(slabS + bOff[1]);        // ph1 kh0
        half8 bc11 = *(const half8*)(slabS + bOff[1] + 16);   // ph1 kh1

        int s = s0;
        for (int si = 0; si < ns; ++si) {
            // ---- issue ALL step-s+1 loads first (A global, k ds, B ds) ----
            uint4 wn0, wn1, wn2, wn3, kn0, kn1;
            half8 bn00, bn01, bn10, bn11;
            int kk2 = kk, ll2 = ll + 1;
            if (ll2 == KS) { ll2 = 0; ++kk2; }
            if (si + 1 < ns) {
                aptr += 65536;
                wn0 = *(const uint4*)(aptr);
                wn1 = *(const uint4*)(aptr + 512);
                wn2 = *(const uint4*)(aptr + 4096);
                wn3 = *(const uint4*)(aptr + 4608);
                const unsigned* kp2 = klds + (size_t)(s + 1) * KPD;
                kn0 = *(const uint4*)(kp2 + half * 4);
                kn1 = *(const uint4*)(kp2 + 8 + half * 4);
                const unsigned short* slabS2 = slab + (kk2 * WW + ll2) * SLAB_PITCH;
                bn00 = *(const half8*)(slabS2 + bOff[0]);
                bn01 = *(const half8*)(slabS2 + bOff[0] + 16);
                bn10 = *(const half8*)(slabS2 + bOff[1]);
                bn11 = *(const half8*)(slabS2 + bOff[1] + 16);
            } else {
                wn0 = wa0; wn1 = wa1; wn2 = wa2; wn3 = wa3;
                kn0 = kc0; kn1 = kc1;
                bn00 = bc00; bn01 = bc01; bn10 = bc10; bn11 = bc11;
            }

            // ---- compute step s from registers only ----
            half8 a00 = mod8(wa0, kc0);  // oh0 kh0
            half8 a10 = mod8(wa1, kc0);  // oh1 kh0
            half8 a01 = mod8(wa2, kc1);  // oh0 kh1
            half8 a11 = mod8(wa3, kc1);  // oh1 kh1

            acc[0][0] = __builtin_amdgcn_mfma_f32_32x32x16_f16(a00, bc00, acc[0][0], 0, 0, 0);
            acc[0][1] = __builtin_amdgcn_mfma_f32_32x32x16_f16(a00, bc10, acc[0][1], 0, 0, 0);
            acc[1][0] = __builtin_amdgcn_mfma_f32_32x32x16_f16(a10, bc00, acc[1][0], 0, 0, 0);
            acc[1][1] = __builtin_amdgcn_mfma_f32_32x32x16_f16(a10, bc10, acc[1][1], 0, 0, 0);
            acc[0][0] = __builtin_amdgcn_mfma_f32_32x32x16_f16(a01, bc01, acc[0][0], 0, 0, 0);
            acc[0][1] = __builtin_amdgcn_mfma_f32_32x32x16_f16(a01, bc11, acc[0][1], 0, 0, 0);
            acc[1][0] = __builtin_amdgcn_mfma_f32_32x32x16_f16(a11, bc01, acc[1][0], 0, 0, 0);
            acc[1][1] = __builtin_amdgcn_mfma_f32_32x32x16_f16(a11, bc11, acc[1][1], 0, 0, 0);

            // ---- rotate pipeline ----
            wa0 = wn0; wa1 = wn1; wa2 = wn2; wa3 = wn3;
            kc0 = kn0; kc1 = kn1;
            bc00 = bn00; bc01 = bn01; bc10 = bn10; bc11 = bn11;
            kk = kk2; ll = ll2; ++s;
        }
    }

    // ---- epilogue: 4-way kw reduction via LDS (reuse slab as red[64p][68]) --
    float* red = (float*)slab;
    __syncthreads();
    if (kw == 3) {
#pragma unroll
        for (int oh = 0; oh < 2; ++oh)
#pragma unroll
            for (int ph = 0; ph < 2; ++ph)
#pragma unroll
                for (int c = 0; c < 4; ++c) {
                    floatx4 v4 = {acc[oh][ph][4*c+0], acc[oh][ph][4*c+1],
                                  acc[oh][ph][4*c+2], acc[oh][ph][4*c+3]};
                    *(floatx4*)(red + (ph * 32 + l32) * 68 + oh * 32 + c * 8 + 4 * half) = v4;
                }
    }
    __syncthreads();
    if (kw == 2) {
#pragma unroll
        for (int oh = 0; oh < 2; ++oh)
#pragma unroll
            for (int ph = 0; ph < 2; ++ph)
#pragma unroll
                for (int c = 0; c < 4; ++c) {
                    float* rp = red + (ph * 32 + l32) * 68 + oh * 32 + c * 8 + 4 * half;
                    floatx4 v4 = *(floatx4*)rp;
                    v4[0] += acc[oh][ph][4*c+0]; v4[1] += acc[oh][ph][4*c+1];
                    v4[2] += acc[oh][ph][4*c+2]; v4[3] += acc[oh][ph][4*c+3];
                    *(floatx4*)rp = v4;
                }
    }
    __syncthreads();
    if (kw == 1) {
#pragma unroll
        for (int oh = 0; oh < 2; ++oh)
#pragma unroll
            for (int ph = 0; ph < 2; ++ph)
#pragma unroll
                for (int c = 0; c < 4; ++c) {
                    float* rp = red + (ph * 32 + l32) * 68 + oh * 32 + c * 8 + 4 * half;
                    floatx4 v4 = *(floatx4*)rp;
                    v4[0] += acc[oh][ph][4*c+0]; v4[1] += acc[oh][ph][4*c+1];
                    v4[2] += acc[oh][ph][4*c+2]; v4[3] += acc[oh][ph][4*c+3];
                    *(floatx4*)rp = v4;
                }
    }
    __syncthreads();
    if (kw == 0) {
#pragma unroll
        for (int oh = 0; oh < 2; ++oh)
#pragma unroll
            for (int c = 0; c < 4; ++c) {
                const int ob = o0 + oh * 32 + c * 8 + 4 * half;
                const float4 bv = *(const float4*)(bias + ob);
#pragma unroll
                for (int ph = 0; ph < 2; ++ph) {
                    const int p = p0 + ph * 32 + l32;
                    floatx4 v4 = *(floatx4*)(red + (ph * 32 + l32) * 68 + oh * 32 + c * 8 + 4 * half);
                    if (p < PP) {
                        out[((size_t)(b * OO + ob + 0)) * PP + p] = v4[0] + acc[oh][ph][4*c+0] + bv.x;
                        out[((size_t)(b * OO + ob + 1)) * PP + p] = v4[1] + acc[oh][ph][4*c+1] + bv.y;
                        out[((size_t)(b * OO + ob + 2)) * PP + p] = v4[2] + acc[oh][ph][4*c+2] + bv.z;
                        out[((size_t)(b * OO + ob + 3)) * PP + p] = v4[3] + acc[oh][ph][4*c+3] + bv.w;
                    }
                }
            }
    }
}

// ---------------------------------------------------------------------------
// Last-resort fallback: naive but correct (ws too small for wt4).
// ---------------------------------------------------------------------------
__global__ __launch_bounds__(256) void dwconv_naive(
        const float* __restrict__ x, const float* __restrict__ kern,
        const float* __restrict__ w, const float* __restrict__ bias,
        float* __restrict__ out) {
    const int idx = blockIdx.x * 256 + threadIdx.x;
    if (idx >= BB * OO * PP) return;
    const int p = idx % PP;
    const int o = (idx / PP) % OO;
    const int b = idx / (PP * OO);
    const int h = p / HO;
    const int wq = p - h * HO;
    float acc = 0.f;
    for (int c = 0; c < CC; ++c) {
        const float* xp = x + ((size_t)(b * CC + c)) * (HH * WW) + h * WW + wq;
        const float* kp = kern + ((size_t)b * CC + c) * SS;
        const float* wp = w + ((size_t)o * CC + c) * SS;
#pragma unroll
        for (int s = 0; s < SS; ++s) {
            const int kk = s / KS;
            const int ll = s - kk * KS;
            acc += xp[kk * WW + ll] * kp[s] * wp[s];
        }
    }
    out[idx] = acc + bias[o];
}

extern "C" void kernel_launch(void* const* d_in, const int* in_sizes, int n_in,
                              void* d_out, int out_size, void* d_ws, size_t ws_size,
                              hipStream_t stream) {
    const float* x    = (const float*)d_in[0];
    const float* kern = (const float*)d_in[1];
    const float* w    = (const float*)d_in[2];
    const float* bias = (const float*)d_in[3];
    float* out = (float*)d_out;

    if (ws_size >= WT4_BYTES) {
        unsigned short* wt4 = (unsigned short*)d_ws;
        repack_w<<<dim3(SS * 8), dim3(256), 0, stream>>>(w, wt4);
        dwconv_fused<<<dim3(1280), dim3(256), 0, stream>>>(x, wt4, kern, bias, out);
    } else {
        const int total = BB * OO * PP;
        dwconv_naive<<<dim3((total + 255) / 256), dim3(256), 0, stream>>>(
            x, kern, w, bias, out);
    }
}